// Round 1
// baseline (596.530 us; speedup 1.0000x reference)
//
#include <hip/hip_runtime.h>
#include <hip/hip_bf16.h>

// AKGCN: B=32,T=16,N=512,C=128,K=2
// out = relu(x) + sigmoid(hid2), hid_{k} = relu(V_k @ (hid_{k-1} @ theta_k))
// V_k = (a I + c adj) row-normalized, a=2-2/lam, c=2/lam, lam=1+relu(lambda_k)
// Folding: out[n,d] = relu( inv[n] * sum_m (adj[n,m] + (lam-1) delta_nm) * h[m,d] )
//          inv[n] = c / (a + c*S[n]),  S = adj row sums.

typedef float f32x4 __attribute__((ext_vector_type(4)));
typedef __bf16 bf16x8 __attribute__((ext_vector_type(8)));

__device__ __forceinline__ unsigned short f2bf(float f) {
  union { float f; unsigned u; } v; v.f = f;
  unsigned r = v.u + 0x7FFFu + ((v.u >> 16) & 1u);
  return (unsigned short)(r >> 16);
}

// ---------------- prep: S rowsums, adjmod (bf16, diag folded, per layer), thetaT bf16
__global__ __launch_bounds__(256) void akgcn_prep(
    const float* __restrict__ adj, const float* __restrict__ lambdas,
    const float* __restrict__ thetas, float* __restrict__ S,
    unsigned short* __restrict__ thT, unsigned short* __restrict__ adjk) {
  int bid = blockIdx.x;
  int tid = threadIdx.x;
  if (bid >= 16384) {           // theta transpose+convert: thT[k][d][c] = theta[k][c][d]
    int k = bid - 16384;
    const float* th = thetas + k * 16384;
    unsigned short* o = thT + k * 16384;
    for (int i = tid; i < 16384; i += 256) {
      int d = i >> 7, c = i & 127;
      o[i] = f2bf(th[c * 128 + d]);
    }
    return;
  }
  int n = bid & 511;
  float2 v = reinterpret_cast<const float2*>(adj + (size_t)bid * 512)[tid];
  float s = v.x + v.y;
#pragma unroll
  for (int off = 32; off > 0; off >>= 1) s += __shfl_down(s, off);
  __shared__ float red[4];
  if ((tid & 63) == 0) red[tid >> 6] = s;
  __syncthreads();
  if (tid == 0) S[bid] = red[0] + red[1] + red[2] + red[3];
  float dg0 = fmaxf(lambdas[0], 0.f);   // lam-1 = relu(raw)
  float dg1 = fmaxf(lambdas[1], 0.f);
  int m = tid * 2;
  ushort2 o0, o1;
  o0.x = f2bf(v.x + (m == n ? dg0 : 0.f));
  o0.y = f2bf(v.y + (m + 1 == n ? dg0 : 0.f));
  o1.x = f2bf(v.x + (m == n ? dg1 : 0.f));
  o1.y = f2bf(v.y + (m + 1 == n ? dg1 : 0.f));
  reinterpret_cast<ushort2*>(adjk + (size_t)bid * 512)[tid] = o0;
  reinterpret_cast<ushort2*>(adjk + 8388608ull + (size_t)bid * 512)[tid] = o1;
}

// ---------------- GEMM1: h = A @ theta_k ; writes hT[bt][d][n] (bf16)
// A: LAYER==0 -> x fp32 [262144,128]; LAYER==1 -> hid1 bf16 [262144,128]
template <int LAYER>
__global__ __launch_bounds__(256) void akgcn_gemm1(
    const void* __restrict__ Ain, const unsigned short* __restrict__ thT,
    unsigned short* __restrict__ hT) {
  __shared__ unsigned short lA[16384];  // [128 rows][128 c], 256B rows, XOR swizzled
  __shared__ unsigned short lB[16384];  // thT tile, same layout
  int bid = blockIdx.x;
  int tid = threadIdx.x;
  size_t r0 = (size_t)bid * 128;
  {
    const unsigned short* src = thT + LAYER * 16384;
#pragma unroll
    for (int it = 0; it < 8; ++it) {
      int idx = it * 2048 + tid * 8;
      uint4 u = *reinterpret_cast<const uint4*>(src + idx);
      int row = idx >> 7;
      unsigned byt = (unsigned)(idx * 2) ^ ((unsigned)(row & 15) << 4);
      *reinterpret_cast<uint4*>((char*)lB + byt) = u;
    }
  }
  if (LAYER == 0) {
    const float* A = (const float*)Ain + r0 * 128;
#pragma unroll
    for (int it = 0; it < 16; ++it) {
      int idx = it * 1024 + tid * 4;
      float4 f = *reinterpret_cast<const float4*>(A + idx);
      int row = idx >> 7;
      unsigned byt = (unsigned)(idx * 2) ^ ((unsigned)(row & 15) << 4);
      ushort4 u;
      u.x = f2bf(f.x); u.y = f2bf(f.y); u.z = f2bf(f.z); u.w = f2bf(f.w);
      *reinterpret_cast<ushort4*>((char*)lA + byt) = u;
    }
  } else {
    const unsigned short* A = (const unsigned short*)Ain + r0 * 128;
#pragma unroll
    for (int it = 0; it < 8; ++it) {
      int idx = it * 2048 + tid * 8;
      uint4 u = *reinterpret_cast<const uint4*>(A + idx);
      int row = idx >> 7;
      unsigned byt = (unsigned)(idx * 2) ^ ((unsigned)(row & 15) << 4);
      *reinterpret_cast<uint4*>((char*)lA + byt) = u;
    }
  }
  __syncthreads();
  int w = tid >> 6, wm = w >> 1, wn = w & 1;
  int lane = tid & 63, lr = lane & 15, lg = lane >> 4;
  f32x4 z = {0.f, 0.f, 0.f, 0.f};
  f32x4 acc[4][4];
#pragma unroll
  for (int mi = 0; mi < 4; ++mi)
#pragma unroll
    for (int ni = 0; ni < 4; ++ni) acc[mi][ni] = z;
#pragma unroll
  for (int ks = 0; ks < 4; ++ks) {
    bf16x8 av[4], bv[4];
#pragma unroll
    for (int mi = 0; mi < 4; ++mi) {
      int row = wm * 64 + mi * 16 + lr;
      unsigned byt = (unsigned)(row * 256 + ks * 64 + lg * 16) ^ ((unsigned)(row & 15) << 4);
      av[mi] = *reinterpret_cast<const bf16x8*>((const char*)lA + byt);
    }
#pragma unroll
    for (int ni = 0; ni < 4; ++ni) {
      int row = wn * 64 + ni * 16 + lr;
      unsigned byt = (unsigned)(row * 256 + ks * 64 + lg * 16) ^ ((unsigned)(row & 15) << 4);
      bv[ni] = *reinterpret_cast<const bf16x8*>((const char*)lB + byt);
    }
#pragma unroll
    for (int mi = 0; mi < 4; ++mi)
#pragma unroll
      for (int ni = 0; ni < 4; ++ni)
        acc[mi][ni] = __builtin_amdgcn_mfma_f32_16x16x32_bf16(av[mi], bv[ni], acc[mi][ni], 0, 0, 0);
  }
  int bt = bid >> 2;
  int n0 = (bid & 3) * 128;
#pragma unroll
  for (int mi = 0; mi < 4; ++mi) {
    int nn = n0 + wm * 64 + mi * 16 + lg * 4;
#pragma unroll
    for (int ni = 0; ni < 4; ++ni) {
      int d = wn * 64 + ni * 16 + lr;
      ushort4 o;
      o.x = f2bf(acc[mi][ni].x); o.y = f2bf(acc[mi][ni].y);
      o.z = f2bf(acc[mi][ni].z); o.w = f2bf(acc[mi][ni].w);
      *reinterpret_cast<ushort4*>(hT + ((size_t)bt * 128 + d) * 512 + nn) = o;
    }
  }
}

// ---------------- GEMM2: out[n,d] = relu(inv[n] * sum_m adjmod[n,m] * h[m,d])
// LAYER==0: write bf16 hid1 into d_out scratch.  LAYER==1: out = relu(x)+sigmoid(v), fp32.
template <int LAYER>
__global__ __launch_bounds__(256) void akgcn_gemm2(
    const unsigned short* __restrict__ adjm, const unsigned short* __restrict__ hT,
    const float* __restrict__ S, const float* __restrict__ lambdas,
    const float* __restrict__ x, void* __restrict__ outp) {
  __shared__ unsigned short lA[2][8192];  // adj tile [128 n][64 m], 128B rows, swizzled
  __shared__ unsigned short lB[2][8192];  // hT  tile [128 d][64 m]
  __shared__ float inv[128];
  int bid0 = blockIdx.x;
  int bid = (bid0 & 7) * 256 + (bid0 >> 3);  // XCD-contiguous (2048 % 8 == 0, bijective)
  int bt = bid >> 2, nb = bid & 3;
  int b = bt >> 4;
  int n0 = nb * 128;
  int tid = threadIdx.x;
  float lam = 1.f + fmaxf(lambdas[LAYER], 0.f);
  float cc = 2.f / lam, aa = 2.f - cc;
  if (tid < 128) inv[tid] = cc / (aa + cc * S[b * 512 + n0 + tid]);
  const unsigned short* Abase = adjm + ((size_t)b * 512 + n0) * 512;
  const unsigned short* Bbase = hT + (size_t)bt * 65536;
  int w = tid >> 6, wm = w >> 1, wn = w & 1;
  int lane = tid & 63, lr = lane & 15, lg = lane >> 4;

  auto stage = [&](int kt, int buf) {
    int m0 = kt * 64;
#pragma unroll
    for (int j = 0; j < 4; ++j) {
      int id = tid + j * 256;
      int row = id >> 3, c = id & 7;
      uint4 ua = *reinterpret_cast<const uint4*>(Abase + (size_t)row * 512 + m0 + c * 8);
      uint4 ub = *reinterpret_cast<const uint4*>(Bbase + (size_t)row * 512 + m0 + c * 8);
      unsigned byt = (unsigned)(row * 128 + c * 16) ^ ((unsigned)(row & 7) << 4);
      *reinterpret_cast<uint4*>((char*)lA[buf] + byt) = ua;
      *reinterpret_cast<uint4*>((char*)lB[buf] + byt) = ub;
    }
  };

  f32x4 z = {0.f, 0.f, 0.f, 0.f};
  f32x4 acc[4][4];
#pragma unroll
  for (int mi = 0; mi < 4; ++mi)
#pragma unroll
    for (int ni = 0; ni < 4; ++ni) acc[mi][ni] = z;

  stage(0, 0);
  __syncthreads();
  for (int kt = 0; kt < 8; ++kt) {
    int buf = kt & 1;
    if (kt < 7) stage(kt + 1, buf ^ 1);
#pragma unroll
    for (int ks = 0; ks < 2; ++ks) {
      bf16x8 av[4], bv[4];
#pragma unroll
      for (int mi = 0; mi < 4; ++mi) {
        int row = wm * 64 + mi * 16 + lr;
        unsigned byt = (unsigned)(row * 128 + ks * 64 + lg * 16) ^ ((unsigned)(row & 7) << 4);
        av[mi] = *reinterpret_cast<const bf16x8*>((const char*)lA[buf] + byt);
      }
#pragma unroll
      for (int ni = 0; ni < 4; ++ni) {
        int row = wn * 64 + ni * 16 + lr;
        unsigned byt = (unsigned)(row * 128 + ks * 64 + lg * 16) ^ ((unsigned)(row & 7) << 4);
        bv[ni] = *reinterpret_cast<const bf16x8*>((const char*)lB[buf] + byt);
      }
#pragma unroll
      for (int mi = 0; mi < 4; ++mi)
#pragma unroll
        for (int ni = 0; ni < 4; ++ni)
          acc[mi][ni] = __builtin_amdgcn_mfma_f32_16x16x32_bf16(av[mi], bv[ni], acc[mi][ni], 0, 0, 0);
    }
    __syncthreads();
  }

  size_t base_bt = (size_t)bt * 512;
#pragma unroll
  for (int mi = 0; mi < 4; ++mi) {
    int nl = wm * 64 + mi * 16 + lg * 4;
#pragma unroll
    for (int ni = 0; ni < 4; ++ni) {
      int d = wn * 64 + ni * 16 + lr;
#pragma unroll
      for (int r = 0; r < 4; ++r) {
        float v = fmaxf(acc[mi][ni][r] * inv[nl + r], 0.f);
        size_t gi = (base_bt + (size_t)(n0 + nl + r)) * 128 + d;
        if (LAYER == 0) {
          ((unsigned short*)outp)[gi] = f2bf(v);
        } else {
          float xv = x[gi];
          ((float*)outp)[gi] = fmaxf(xv, 0.f) + 1.f / (1.f + __expf(-v));
        }
      }
    }
  }
}

extern "C" void kernel_launch(void* const* d_in, const int* in_sizes, int n_in,
                              void* d_out, int out_size, void* d_ws, size_t ws_size,
                              hipStream_t stream) {
  const float* x = (const float*)d_in[0];
  const float* adj = (const float*)d_in[1];
  const float* lambdas = (const float*)d_in[2];
  const float* thetas = (const float*)d_in[3];
  char* ws = (char*)d_ws;
  float* S = (float*)ws;                                   // 64 KiB
  unsigned short* thT = (unsigned short*)(ws + 65536);     // 64 KiB
  unsigned short* adjk = (unsigned short*)(ws + 131072);   // 2 x 16 MiB
  unsigned short* hT = (unsigned short*)(ws + 131072 + 33554432);  // 64 MiB
  unsigned short* hid1 = (unsigned short*)d_out;           // 64 MiB scratch inside d_out

  akgcn_prep<<<16386, 256, 0, stream>>>(adj, lambdas, thetas, S, thT, adjk);
  akgcn_gemm1<0><<<2048, 256, 0, stream>>>((const void*)x, thT, hT);
  akgcn_gemm2<0><<<2048, 256, 0, stream>>>(adjk, hT, S, lambdas, nullptr, (void*)hid1);
  akgcn_gemm1<1><<<2048, 256, 0, stream>>>((const void*)hid1, thT, hT);
  akgcn_gemm2<1><<<2048, 256, 0, stream>>>(adjk + 8388608ull, hT, S, lambdas, x, d_out);
}

// Round 2
// 468.991 us; speedup vs baseline: 1.2719x; 1.2719x over previous
//
#include <hip/hip_runtime.h>
#include <hip/hip_bf16.h>

// AKGCN: B=32,T=16,N=512,C=128,K=2
// out = relu(x) + sigmoid(hid2), hid_k = relu(V_k @ (hid_{k-1} @ theta_k))
// Folding: out[n,d] = relu( inv[n] * sum_m (adj[n,m] + (lam-1) delta_nm) * h[m,d] )
//          inv[n] = c / (a + c*S[n]),  a=2-2/lam, c=2/lam, S = adj row sums.

typedef float f32x4 __attribute__((ext_vector_type(4)));
typedef __bf16 bf16x8 __attribute__((ext_vector_type(8)));

__device__ __forceinline__ unsigned short f2bf(float f) {
  union { float f; unsigned u; } v; v.f = f;
  unsigned r = v.u + 0x7FFFu + ((v.u >> 16) & 1u);
  return (unsigned short)(r >> 16);
}

__device__ __forceinline__ void gld16(const void* g, void* l) {
  __builtin_amdgcn_global_load_lds((const __attribute__((address_space(1))) void*)g,
                                   (__attribute__((address_space(3))) void*)l, 16, 0, 0);
}

// ---------------- prep: S rowsums, adjmod (bf16, diag folded, per layer), thetaT bf16
__global__ __launch_bounds__(256) void akgcn_prep(
    const float* __restrict__ adj, const float* __restrict__ lambdas,
    const float* __restrict__ thetas, float* __restrict__ S,
    unsigned short* __restrict__ thT, unsigned short* __restrict__ adjk) {
  int bid = blockIdx.x;
  int tid = threadIdx.x;
  if (bid >= 16384) {           // theta transpose+convert: thT[k][d][c] = theta[k][c][d]
    int k = bid - 16384;
    const float* th = thetas + k * 16384;
    unsigned short* o = thT + k * 16384;
    for (int i = tid; i < 16384; i += 256) {
      int d = i >> 7, c = i & 127;
      o[i] = f2bf(th[c * 128 + d]);
    }
    return;
  }
  int n = bid & 511;
  float2 v = reinterpret_cast<const float2*>(adj + (size_t)bid * 512)[tid];
  float s = v.x + v.y;
#pragma unroll
  for (int off = 32; off > 0; off >>= 1) s += __shfl_down(s, off);
  __shared__ float red[4];
  if ((tid & 63) == 0) red[tid >> 6] = s;
  __syncthreads();
  if (tid == 0) S[bid] = red[0] + red[1] + red[2] + red[3];
  float dg0 = fmaxf(lambdas[0], 0.f);   // lam-1 = relu(raw)
  float dg1 = fmaxf(lambdas[1], 0.f);
  int m = tid * 2;
  ushort2 o0, o1;
  o0.x = f2bf(v.x + (m == n ? dg0 : 0.f));
  o0.y = f2bf(v.y + (m + 1 == n ? dg0 : 0.f));
  o1.x = f2bf(v.x + (m == n ? dg1 : 0.f));
  o1.y = f2bf(v.y + (m + 1 == n ? dg1 : 0.f));
  reinterpret_cast<ushort2*>(adjk + (size_t)bid * 512)[tid] = o0;
  reinterpret_cast<ushort2*>(adjk + 8388608ull + (size_t)bid * 512)[tid] = o1;
}

// ---------------- GEMM1: h = A @ theta_k ; writes hT[bt][d][n] (bf16), coalesced via LDS transpose
// A: LAYER==0 -> x fp32 [262144,128]; LAYER==1 -> hid1 bf16 [262144,128]
template <int LAYER>
__global__ __launch_bounds__(256) void akgcn_gemm1(
    const void* __restrict__ Ain, const unsigned short* __restrict__ thT,
    unsigned short* __restrict__ hT) {
  __shared__ unsigned short sm[32768];       // 64 KB: lA | lB, reused as transpose buffer
  unsigned short* lA = sm;                   // [128 rows][128 c], 256B rows, XOR swizzled
  unsigned short* lB = sm + 16384;
  int bid = blockIdx.x;
  int tid = threadIdx.x;
  size_t r0 = (size_t)bid * 128;
  {
    const unsigned short* src = thT + LAYER * 16384;
#pragma unroll
    for (int it = 0; it < 8; ++it) {
      int idx = it * 2048 + tid * 8;
      uint4 u = *reinterpret_cast<const uint4*>(src + idx);
      int row = idx >> 7;
      unsigned byt = (unsigned)(idx * 2) ^ ((unsigned)(row & 15) << 4);
      *reinterpret_cast<uint4*>((char*)lB + byt) = u;
    }
  }
  if (LAYER == 0) {
    const float* A = (const float*)Ain + r0 * 128;
#pragma unroll
    for (int it = 0; it < 16; ++it) {
      int idx = it * 1024 + tid * 4;
      float4 f = *reinterpret_cast<const float4*>(A + idx);
      int row = idx >> 7;
      unsigned byt = (unsigned)(idx * 2) ^ ((unsigned)(row & 15) << 4);
      ushort4 u;
      u.x = f2bf(f.x); u.y = f2bf(f.y); u.z = f2bf(f.z); u.w = f2bf(f.w);
      *reinterpret_cast<ushort4*>((char*)lA + byt) = u;
    }
  } else {
    const unsigned short* A = (const unsigned short*)Ain + r0 * 128;
#pragma unroll
    for (int it = 0; it < 8; ++it) {
      int idx = it * 2048 + tid * 8;
      uint4 u = *reinterpret_cast<const uint4*>(A + idx);
      int row = idx >> 7;
      unsigned byt = (unsigned)(idx * 2) ^ ((unsigned)(row & 15) << 4);
      *reinterpret_cast<uint4*>((char*)lA + byt) = u;
    }
  }
  __syncthreads();
  int w = tid >> 6, wm = w >> 1, wn = w & 1;
  int lane = tid & 63, lr = lane & 15, lg = lane >> 4;
  f32x4 z = {0.f, 0.f, 0.f, 0.f};
  f32x4 acc[4][4];
#pragma unroll
  for (int mi = 0; mi < 4; ++mi)
#pragma unroll
    for (int ni = 0; ni < 4; ++ni) acc[mi][ni] = z;
#pragma unroll
  for (int ks = 0; ks < 4; ++ks) {
    bf16x8 av[4], bv[4];
#pragma unroll
    for (int mi = 0; mi < 4; ++mi) {
      int row = wm * 64 + mi * 16 + lr;
      unsigned byt = (unsigned)(row * 256 + ks * 64 + lg * 16) ^ ((unsigned)(row & 15) << 4);
      av[mi] = *reinterpret_cast<const bf16x8*>((const char*)lA + byt);
    }
#pragma unroll
    for (int ni = 0; ni < 4; ++ni) {
      int row = wn * 64 + ni * 16 + lr;
      unsigned byt = (unsigned)(row * 256 + ks * 64 + lg * 16) ^ ((unsigned)(row & 15) << 4);
      bv[ni] = *reinterpret_cast<const bf16x8*>((const char*)lB + byt);
    }
#pragma unroll
    for (int mi = 0; mi < 4; ++mi)
#pragma unroll
      for (int ni = 0; ni < 4; ++ni)
        acc[mi][ni] = __builtin_amdgcn_mfma_f32_16x16x32_bf16(av[mi], bv[ni], acc[mi][ni], 0, 0, 0);
  }
  // transpose acc -> LDS [d][n'] (row stride 136 shorts = 272 B: 16B-aligned rows, bank-safe)
  __syncthreads();  // all LDS frag reads done before overwrite
#pragma unroll
  for (int mi = 0; mi < 4; ++mi) {
    int nloc = wm * 64 + mi * 16 + lg * 4;   // D row = n' (4 consecutive per lane)
#pragma unroll
    for (int ni = 0; ni < 4; ++ni) {
      int d = wn * 64 + ni * 16 + lr;        // D col = d
      ushort4 o;
      o.x = f2bf(acc[mi][ni][0]); o.y = f2bf(acc[mi][ni][1]);
      o.z = f2bf(acc[mi][ni][2]); o.w = f2bf(acc[mi][ni][3]);
      *reinterpret_cast<ushort4*>((char*)sm + d * 272 + nloc * 2) = o;
    }
  }
  __syncthreads();
  int bt = bid >> 2, n0 = (bid & 3) * 128;
#pragma unroll
  for (int i = 0; i < 8; ++i) {
    int c = i * 256 + tid;          // 2048 chunks of 16 B
    int dr = c >> 4, c8 = c & 15;
    uint4 u = *reinterpret_cast<const uint4*>((const char*)sm + dr * 272 + c8 * 16);
    *reinterpret_cast<uint4*>(hT + ((size_t)bt * 128 + dr) * 512 + n0 + c8 * 8) = u;
  }
}

// ---------------- GEMM2: out[n,d] = relu(inv[n] * sum_m adjmod[n,m] * h[m,d])
// A-operand = hT rows (d), B-operand = adj rows (n) -> D[row=d][col=n]; lane holds 4
// consecutive d -> vectorized epilogue. global_load_lds staging, linear LDS.
template <int LAYER>
__global__ __launch_bounds__(256) void akgcn_gemm2(
    const unsigned short* __restrict__ adjm, const unsigned short* __restrict__ hT,
    const float* __restrict__ S, const float* __restrict__ lambdas,
    const float* __restrict__ x, void* __restrict__ outp) {
  __shared__ unsigned short ldsA[2][8192];  // adj tile [128 n][64 m] linear, 128B rows
  __shared__ unsigned short ldsH[2][8192];  // hT  tile [128 d][64 m] linear
  __shared__ float inv[128];
  int tid = threadIdx.x;
  // work order: t innermost (adj reuse), XCD-chunked (2048 % 8 == 0, bijective)
  int wk = (blockIdx.x & 7) * 256 + (blockIdx.x >> 3);
  int b = wk >> 6, nb = (wk >> 4) & 3, t = wk & 15;
  int bt = b * 16 + t, n0 = nb * 128;
  float lam = 1.f + fmaxf(lambdas[LAYER], 0.f);
  float cc = 2.f / lam, aa = 2.f - cc;
  if (tid < 128) inv[tid] = cc / (aa + cc * S[b * 512 + n0 + tid]);
  const unsigned short* Abase = adjm + ((size_t)b * 512 + n0) * 512;
  const unsigned short* Hbase = hT + (size_t)bt * 65536;
  int w = tid >> 6, ln = tid & 63;
  int lr = ln & 15, lg = ln >> 4;
  int wm = w >> 1, wn = w & 1;      // wm: d-half, wn: n-half
  int rsub = ln >> 3, c16 = ln & 7; // staging: 8 lanes per row, 16B chunks

  auto stage = [&](int kt, int buf) {
    int m0 = kt * 64;
#pragma unroll
    for (int j = 0; j < 4; ++j) {
      int row = w * 32 + j * 8;     // wave-uniform LDS row base
      gld16(Abase + (size_t)(row + rsub) * 512 + m0 + c16 * 8, &ldsA[buf][row * 64]);
      gld16(Hbase + (size_t)(row + rsub) * 512 + m0 + c16 * 8, &ldsH[buf][row * 64]);
    }
  };

  f32x4 z = {0.f, 0.f, 0.f, 0.f};
  f32x4 acc[4][4];
#pragma unroll
  for (int mi = 0; mi < 4; ++mi)
#pragma unroll
    for (int ni = 0; ni < 4; ++ni) acc[mi][ni] = z;

  stage(0, 0);
  __syncthreads();
  for (int kt = 0; kt < 8; ++kt) {
    int buf = kt & 1;
    if (kt < 7) stage(kt + 1, buf ^ 1);
#pragma unroll
    for (int ks = 0; ks < 2; ++ks) {
      bf16x8 av[4], bv[4];
#pragma unroll
      for (int mi = 0; mi < 4; ++mi) {       // d-frags from hT tile
        int row = wm * 64 + mi * 16 + lr;
        av[mi] = *reinterpret_cast<const bf16x8*>((const char*)ldsH[buf] + row * 128 + ks * 64 + lg * 16);
      }
#pragma unroll
      for (int ni = 0; ni < 4; ++ni) {       // n-frags from adj tile
        int row = wn * 64 + ni * 16 + lr;
        bv[ni] = *reinterpret_cast<const bf16x8*>((const char*)ldsA[buf] + row * 128 + ks * 64 + lg * 16);
      }
#pragma unroll
      for (int mi = 0; mi < 4; ++mi)
#pragma unroll
        for (int ni = 0; ni < 4; ++ni)
          acc[mi][ni] = __builtin_amdgcn_mfma_f32_16x16x32_bf16(av[mi], bv[ni], acc[mi][ni], 0, 0, 0);
    }
    __syncthreads();
  }

  // epilogue: D row = d = wm*64+mi*16+lg*4+r (4 consecutive d per lane), col = n = wn*64+ni*16+lr
  size_t base_bt = (size_t)bt * 512;
#pragma unroll
  for (int ni = 0; ni < 4; ++ni) {
    int nl = wn * 64 + ni * 16 + lr;
    float iv = inv[nl];
    size_t rowbase = (base_bt + (size_t)(n0 + nl)) * 128;
#pragma unroll
    for (int mi = 0; mi < 4; ++mi) {
      int d0 = wm * 64 + mi * 16 + lg * 4;
      f32x4 a = acc[mi][ni];
      if (LAYER == 0) {
        ushort4 o;
        o.x = f2bf(fmaxf(a[0] * iv, 0.f)); o.y = f2bf(fmaxf(a[1] * iv, 0.f));
        o.z = f2bf(fmaxf(a[2] * iv, 0.f)); o.w = f2bf(fmaxf(a[3] * iv, 0.f));
        *reinterpret_cast<ushort4*>((unsigned short*)outp + rowbase + d0) = o;
      } else {
        float4 xv = *reinterpret_cast<const float4*>(x + rowbase + d0);
        float4 o;
        o.x = fmaxf(xv.x, 0.f) + 1.f / (1.f + __expf(-fmaxf(a[0] * iv, 0.f)));
        o.y = fmaxf(xv.y, 0.f) + 1.f / (1.f + __expf(-fmaxf(a[1] * iv, 0.f)));
        o.z = fmaxf(xv.z, 0.f) + 1.f / (1.f + __expf(-fmaxf(a[2] * iv, 0.f)));
        o.w = fmaxf(xv.w, 0.f) + 1.f / (1.f + __expf(-fmaxf(a[3] * iv, 0.f)));
        *reinterpret_cast<float4*>((float*)outp + rowbase + d0) = o;
      }
    }
  }
}

extern "C" void kernel_launch(void* const* d_in, const int* in_sizes, int n_in,
                              void* d_out, int out_size, void* d_ws, size_t ws_size,
                              hipStream_t stream) {
  const float* x = (const float*)d_in[0];
  const float* adj = (const float*)d_in[1];
  const float* lambdas = (const float*)d_in[2];
  const float* thetas = (const float*)d_in[3];
  char* ws = (char*)d_ws;
  float* S = (float*)ws;                                   // 64 KiB
  unsigned short* thT = (unsigned short*)(ws + 65536);     // 64 KiB
  unsigned short* adjk = (unsigned short*)(ws + 131072);   // 2 x 16 MiB
  unsigned short* hT = (unsigned short*)(ws + 131072 + 33554432);  // 64 MiB
  unsigned short* hid1 = (unsigned short*)d_out;           // 64 MiB scratch inside d_out

  akgcn_prep<<<16386, 256, 0, stream>>>(adj, lambdas, thetas, S, thT, adjk);
  akgcn_gemm1<0><<<2048, 256, 0, stream>>>((const void*)x, thT, hT);
  akgcn_gemm2<0><<<2048, 256, 0, stream>>>(adjk, hT, S, lambdas, nullptr, (void*)hid1);
  akgcn_gemm1<1><<<2048, 256, 0, stream>>>((const void*)hid1, thT, hT);
  akgcn_gemm2<1><<<2048, 256, 0, stream>>>(adjk + 8388608ull, hT, S, lambdas, x, d_out);
}

// Round 4
// 430.395 us; speedup vs baseline: 1.3860x; 1.0897x over previous
//
#include <hip/hip_runtime.h>
#include <hip/hip_bf16.h>

// AKGCN: B=32,T=16,N=512,C=128,K=2
// out = relu(x) + sigmoid(hid2), hid_k = relu(V_k @ (hid_{k-1} @ theta_k))
// Folding: out[n,d] = relu( inv[n] * sum_m (adj[n,m] + (lam-1) delta_nm) * h[m,d] )
//          inv[n] = c / (a + c*S[n]),  a=2-2/lam, c=2/lam, S = adj row sums.
// Pipeline: prep -> gemm1<x@th0 -> hT(d_out)> -> gemm2<0> fused(th1) -> hT2(ws) -> gemm2<1> -> out.

typedef float f32x4 __attribute__((ext_vector_type(4)));
typedef __bf16 bf16x8 __attribute__((ext_vector_type(8)));

__device__ __forceinline__ unsigned short f2bf(float f) {
  union { float f; unsigned u; } v; v.f = f;
  unsigned r = v.u + 0x7FFFu + ((v.u >> 16) & 1u);
  return (unsigned short)(r >> 16);
}

__device__ __forceinline__ void gld16(const void* g, void* l) {
  __builtin_amdgcn_global_load_lds((const __attribute__((address_space(1))) void*)g,
                                   (__attribute__((address_space(3))) void*)l, 16, 0, 0);
}

// ---------------- prep: S rowsums, adjmod (bf16, diag folded, per layer), thetaT bf16
__global__ __launch_bounds__(256) void akgcn_prep(
    const float* __restrict__ adj, const float* __restrict__ lambdas,
    const float* __restrict__ thetas, float* __restrict__ S,
    unsigned short* __restrict__ thT, unsigned short* __restrict__ adjk) {
  int bid = blockIdx.x;
  int tid = threadIdx.x;
  if (bid >= 16384) {           // theta transpose+convert: thT[k][d][c] = theta[k][c][d]
    int k = bid - 16384;
    const float* th = thetas + k * 16384;
    unsigned short* o = thT + k * 16384;
    for (int i = tid; i < 16384; i += 256) {
      int d = i >> 7, c = i & 127;
      o[i] = f2bf(th[c * 128 + d]);
    }
    return;
  }
  int n = bid & 511;
  float2 v = reinterpret_cast<const float2*>(adj + (size_t)bid * 512)[tid];
  float s = v.x + v.y;
#pragma unroll
  for (int off = 32; off > 0; off >>= 1) s += __shfl_down(s, off);
  __shared__ float red[4];
  if ((tid & 63) == 0) red[tid >> 6] = s;
  __syncthreads();
  if (tid == 0) S[bid] = red[0] + red[1] + red[2] + red[3];
  float dg0 = fmaxf(lambdas[0], 0.f);   // lam-1 = relu(raw)
  float dg1 = fmaxf(lambdas[1], 0.f);
  int m = tid * 2;
  ushort2 o0, o1;
  o0.x = f2bf(v.x + (m == n ? dg0 : 0.f));
  o0.y = f2bf(v.y + (m + 1 == n ? dg0 : 0.f));
  o1.x = f2bf(v.x + (m == n ? dg1 : 0.f));
  o1.y = f2bf(v.y + (m + 1 == n ? dg1 : 0.f));
  reinterpret_cast<ushort2*>(adjk + (size_t)bid * 512)[tid] = o0;
  reinterpret_cast<ushort2*>(adjk + 8388608ull + (size_t)bid * 512)[tid] = o1;
}

// ---------------- GEMM1: h = x @ theta0 ; writes hT[bt][d][n] (bf16) via LDS transpose
__global__ __launch_bounds__(256) void akgcn_gemm1(
    const float* __restrict__ x, const unsigned short* __restrict__ thT,
    unsigned short* __restrict__ hT) {
  __shared__ unsigned short sm[32768];       // 64 KB: lA | lB, reused as transpose buffer
  unsigned short* lA = sm;                   // [128 rows][128 c], 256B rows, XOR swizzled
  unsigned short* lB = sm + 16384;
  int bid = blockIdx.x;
  int tid = threadIdx.x;
  size_t r0 = (size_t)bid * 128;
  {
#pragma unroll
    for (int it = 0; it < 8; ++it) {
      int idx = it * 2048 + tid * 8;
      uint4 u = *reinterpret_cast<const uint4*>(thT + idx);
      int row = idx >> 7;
      unsigned byt = (unsigned)(idx * 2) ^ ((unsigned)(row & 15) << 4);
      *reinterpret_cast<uint4*>((char*)lB + byt) = u;
    }
  }
  {
    const float* A = x + r0 * 128;
#pragma unroll
    for (int it = 0; it < 16; ++it) {
      int idx = it * 1024 + tid * 4;
      float4 f = *reinterpret_cast<const float4*>(A + idx);
      int row = idx >> 7;
      unsigned byt = (unsigned)(idx * 2) ^ ((unsigned)(row & 15) << 4);
      ushort4 u;
      u.x = f2bf(f.x); u.y = f2bf(f.y); u.z = f2bf(f.z); u.w = f2bf(f.w);
      *reinterpret_cast<ushort4*>((char*)lA + byt) = u;
    }
  }
  __syncthreads();
  int w = tid >> 6, wm = w >> 1, wn = w & 1;
  int lane = tid & 63, lr = lane & 15, lg = lane >> 4;
  f32x4 z = {0.f, 0.f, 0.f, 0.f};
  f32x4 acc[4][4];
#pragma unroll
  for (int mi = 0; mi < 4; ++mi)
#pragma unroll
    for (int ni = 0; ni < 4; ++ni) acc[mi][ni] = z;
#pragma unroll
  for (int ks = 0; ks < 4; ++ks) {
    bf16x8 av[4], bv[4];
#pragma unroll
    for (int mi = 0; mi < 4; ++mi) {
      int row = wm * 64 + mi * 16 + lr;
      unsigned byt = (unsigned)(row * 256 + ks * 64 + lg * 16) ^ ((unsigned)(row & 15) << 4);
      av[mi] = *reinterpret_cast<const bf16x8*>((const char*)lA + byt);
    }
#pragma unroll
    for (int ni = 0; ni < 4; ++ni) {
      int row = wn * 64 + ni * 16 + lr;
      unsigned byt = (unsigned)(row * 256 + ks * 64 + lg * 16) ^ ((unsigned)(row & 15) << 4);
      bv[ni] = *reinterpret_cast<const bf16x8*>((const char*)lB + byt);
    }
#pragma unroll
    for (int mi = 0; mi < 4; ++mi)
#pragma unroll
      for (int ni = 0; ni < 4; ++ni)
        acc[mi][ni] = __builtin_amdgcn_mfma_f32_16x16x32_bf16(av[mi], bv[ni], acc[mi][ni], 0, 0, 0);
  }
  // transpose acc -> LDS [d][n'] (row stride 272 B), then coalesced global store
  __syncthreads();
#pragma unroll
  for (int mi = 0; mi < 4; ++mi) {
    int nloc = wm * 64 + mi * 16 + lg * 4;   // D row = A-index = n (4 consecutive per lane)
#pragma unroll
    for (int ni = 0; ni < 4; ++ni) {
      int d = wn * 64 + ni * 16 + lr;        // D col = B-index = d
      ushort4 o;
      o.x = f2bf(acc[mi][ni][0]); o.y = f2bf(acc[mi][ni][1]);
      o.z = f2bf(acc[mi][ni][2]); o.w = f2bf(acc[mi][ni][3]);
      *reinterpret_cast<ushort4*>((char*)sm + d * 272 + nloc * 2) = o;
    }
  }
  __syncthreads();
  int bt = bid >> 2, n0 = (bid & 3) * 128;
#pragma unroll
  for (int i = 0; i < 8; ++i) {
    int c = i * 256 + tid;          // 2048 chunks of 16 B
    int dr = c >> 4, c8 = c & 15;
    uint4 u = *reinterpret_cast<const uint4*>((const char*)sm + dr * 272 + c8 * 16);
    *reinterpret_cast<uint4*>(hT + ((size_t)bt * 128 + dr) * 512 + n0 + c8 * 8) = u;
  }
}

// ---------------- GEMM2 (fused for LAYER==0): out_tile = relu(inv * Vadj @ h)
// A-operand = hT rows (d, k=m), B-operand = adj rows (n, k=m) -> D[row=d][col=n].
// Staging: global_load_lds, linear dest, inverse-swizzled source, XOR-swizzled reads (T2).
// K-loop: counted vmcnt(8) double-buffer, raw barriers (T4).
// LAYER==0 epilogue: hid tile -> LDS, @ theta1 -> write hT2[bt][e][n] (fuses gemm1<1>).
// LAYER==1 epilogue: out = relu(x) + sigmoid(hid2), fp32.
template <int LAYER>
__global__ __launch_bounds__(256) void akgcn_gemm2(
    const unsigned short* __restrict__ adjm, const unsigned short* __restrict__ hT,
    const float* __restrict__ S, const float* __restrict__ lambdas,
    const float* __restrict__ x, const unsigned short* __restrict__ thT1,
    void* __restrict__ outp) {
  __shared__ unsigned short ldsA[2][8192];  // adj tile [128 n][64 m], swizzled
  __shared__ unsigned short ldsH[2][8192];  // hT  tile [128 d][64 m], swizzled
  int tid = threadIdx.x;
  // work order: t innermost (adj L2 reuse), XCD-chunked (2048 % 8 == 0, bijective)
  int wk = (blockIdx.x & 7) * 256 + (blockIdx.x >> 3);
  int b = wk >> 6, nb = (wk >> 4) & 3, t = wk & 15;
  int bt = b * 16 + t, n0 = nb * 128;
  float lam = 1.f + fmaxf(lambdas[LAYER], 0.f);
  float cc = 2.f / lam, aa = 2.f - cc;
  const unsigned short* Abase = adjm + ((size_t)b * 512 + n0) * 512;
  const unsigned short* Hbase = hT + (size_t)bt * 65536;
  int w = tid >> 6, ln = tid & 63;
  int lr = ln & 15, lg = ln >> 4;
  int wm = w >> 1, wn = w & 1;      // wm: d-half, wn: n-half
  int rsub = ln >> 3, c16 = ln & 7; // staging: 8 lanes per 128B row, 16B chunks

  auto stage = [&](int kt, int buf) {
    int m0 = kt * 64;
    int scol = m0 + ((c16 ^ rsub) << 3);  // inverse-swizzle source (rule #21)
#pragma unroll
    for (int j = 0; j < 4; ++j) {
      int rowb = w * 32 + j * 8;          // wave-uniform LDS row base
      gld16(Abase + (size_t)(rowb + rsub) * 512 + scol, &ldsA[buf][rowb * 64]);
      gld16(Hbase + (size_t)(rowb + rsub) * 512 + scol, &ldsH[buf][rowb * 64]);
    }
  };

  f32x4 z = {0.f, 0.f, 0.f, 0.f};
  f32x4 acc[4][4];
#pragma unroll
  for (int mi = 0; mi < 4; ++mi)
#pragma unroll
    for (int ni = 0; ni < 4; ++ni) acc[mi][ni] = z;

  stage(0, 0);
  for (int kt = 0; kt < 8; ++kt) {
    int buf = kt & 1;
    if (kt < 7) {
      stage(kt + 1, buf ^ 1);
      asm volatile("s_waitcnt vmcnt(8)" ::: "memory");  // kt's 8 loads done; kt+1 in flight
    } else {
      asm volatile("s_waitcnt vmcnt(0)" ::: "memory");
    }
    __builtin_amdgcn_s_barrier();       // buf[kt] published
#pragma unroll
    for (int ks = 0; ks < 2; ++ks) {
      bf16x8 av[4], bv[4];
#pragma unroll
      for (int mi = 0; mi < 4; ++mi) {       // d-frags from hT tile
        int row = wm * 64 + mi * 16 + lr;
        unsigned byt = (unsigned)(row * 128 + ks * 64 + lg * 16) ^ ((unsigned)(row & 7) << 4);
        av[mi] = *reinterpret_cast<const bf16x8*>((const char*)ldsH[buf] + byt);
      }
#pragma unroll
      for (int ni = 0; ni < 4; ++ni) {       // n-frags from adj tile
        int row = wn * 64 + ni * 16 + lr;
        unsigned byt = (unsigned)(row * 128 + ks * 64 + lg * 16) ^ ((unsigned)(row & 7) << 4);
        bv[ni] = *reinterpret_cast<const bf16x8*>((const char*)ldsA[buf] + byt);
      }
#pragma unroll
      for (int mi = 0; mi < 4; ++mi)
#pragma unroll
        for (int ni = 0; ni < 4; ++ni)
          acc[mi][ni] = __builtin_amdgcn_mfma_f32_16x16x32_bf16(av[mi], bv[ni], acc[mi][ni], 0, 0, 0);
    }
    __builtin_amdgcn_s_barrier();       // all reads of buf[kt] done before overwrite
  }

  // per-lane inv (S is tiny & L2-hot; avoids LDS + cross-wave visibility under raw barriers)
  float invv[4];
#pragma unroll
  for (int ni = 0; ni < 4; ++ni)
    invv[ni] = cc / (aa + cc * S[b * 512 + n0 + wn * 64 + ni * 16 + lr]);

  if (LAYER == 0) {
    // ---- fused second-half: hid tile (relu'd, bf16) -> LDS; @ theta1 -> hT2[bt][e][n]
    unsigned short* hidT = &ldsA[0][0];   // [128 n][128 d], 256B rows, XOR ((n&15)<<4)
    unsigned short* thL = &ldsH[0][0];    // [128 e][128 d], same swizzle
#pragma unroll
    for (int ni = 0; ni < 4; ++ni) {
      int n = wn * 64 + ni * 16 + lr;
      float iv = invv[ni];
#pragma unroll
      for (int mi = 0; mi < 4; ++mi) {
        int d0 = wm * 64 + mi * 16 + lg * 4;
        f32x4 a = acc[mi][ni];
        ushort4 o;
        o.x = f2bf(fmaxf(a[0] * iv, 0.f)); o.y = f2bf(fmaxf(a[1] * iv, 0.f));
        o.z = f2bf(fmaxf(a[2] * iv, 0.f)); o.w = f2bf(fmaxf(a[3] * iv, 0.f));
        unsigned byt = (unsigned)(n * 256 + d0 * 2) ^ ((unsigned)(n & 15) << 4);
        *reinterpret_cast<ushort4*>((char*)hidT + byt) = o;
      }
    }
    // stage theta1^T [e][d] (8 gld16/wave), inverse-swizzled source
#pragma unroll
    for (int j = 0; j < 8; ++j) {
      int rowb = w * 32 + j * 4;          // wave-uniform, 4 rows of 256B per gld16
      int row = rowb + (ln >> 4);
      int c = ln & 15;
      gld16(thT1 + (size_t)row * 128 + ((c ^ (row & 15)) << 3), &thL[rowb * 128]);
    }
    __syncthreads();                      // full drain: ds_writes + theta loads
    f32x4 acc2[4][4];
#pragma unroll
    for (int mi = 0; mi < 4; ++mi)
#pragma unroll
      for (int ni = 0; ni < 4; ++ni) acc2[mi][ni] = z;
#pragma unroll
    for (int ks = 0; ks < 4; ++ks) {
      bf16x8 av[4], bv[4];
#pragma unroll
      for (int mi = 0; mi < 4; ++mi) {       // hid rows (n), k = d
        int n = wm * 64 + mi * 16 + lr;
        unsigned byt = (unsigned)(n * 256 + ks * 64 + lg * 16) ^ ((unsigned)(n & 15) << 4);
        av[mi] = *reinterpret_cast<const bf16x8*>((const char*)hidT + byt);
      }
#pragma unroll
      for (int ni = 0; ni < 4; ++ni) {       // theta1^T rows (e), k = d
        int e = wn * 64 + ni * 16 + lr;
        unsigned byt = (unsigned)(e * 256 + ks * 64 + lg * 16) ^ ((unsigned)(e & 15) << 4);
        bv[ni] = *reinterpret_cast<const bf16x8*>((const char*)thL + byt);
      }
#pragma unroll
      for (int mi = 0; mi < 4; ++mi)
#pragma unroll
        for (int ni = 0; ni < 4; ++ni)
          acc2[mi][ni] = __builtin_amdgcn_mfma_f32_16x16x32_bf16(av[mi], bv[ni], acc2[mi][ni], 0, 0, 0);
    }
    // store hT2[bt][e][n0+n]: D rows = n (4 consec per lane) -> direct ushort4 along n
    unsigned short* hT2 = (unsigned short*)outp;
#pragma unroll
    for (int ni = 0; ni < 4; ++ni) {
      int e = wn * 64 + ni * 16 + lr;
      unsigned short* dst = hT2 + ((size_t)bt * 128 + e) * 512 + n0;
#pragma unroll
      for (int mi = 0; mi < 4; ++mi) {
        int nn = wm * 64 + mi * 16 + lg * 4;
        f32x4 a = acc2[mi][ni];
        ushort4 o;
        o.x = f2bf(a[0]); o.y = f2bf(a[1]); o.z = f2bf(a[2]); o.w = f2bf(a[3]);
        *reinterpret_cast<ushort4*>(dst + nn) = o;
      }
    }
  } else {
    // ---- final epilogue: out = relu(x) + sigmoid(relu(inv*acc)), fp32
#pragma unroll
    for (int ni = 0; ni < 4; ++ni) {
      int nl = wn * 64 + ni * 16 + lr;
      float iv = invv[ni];
      size_t rowbase = ((size_t)bt * 512 + (size_t)(n0 + nl)) * 128;
#pragma unroll
      for (int mi = 0; mi < 4; ++mi) {
        int d0 = wm * 64 + mi * 16 + lg * 4;
        f32x4 a = acc[mi][ni];
        float4 xv = *reinterpret_cast<const float4*>(x + rowbase + d0);
        float4 o;
        o.x = fmaxf(xv.x, 0.f) + 1.f / (1.f + __expf(-fmaxf(a[0] * iv, 0.f)));
        o.y = fmaxf(xv.y, 0.f) + 1.f / (1.f + __expf(-fmaxf(a[1] * iv, 0.f)));
        o.z = fmaxf(xv.z, 0.f) + 1.f / (1.f + __expf(-fmaxf(a[2] * iv, 0.f)));
        o.w = fmaxf(xv.w, 0.f) + 1.f / (1.f + __expf(-fmaxf(a[3] * iv, 0.f)));
        *reinterpret_cast<float4*>((float*)outp + rowbase + d0) = o;
      }
    }
  }
}

extern "C" void kernel_launch(void* const* d_in, const int* in_sizes, int n_in,
                              void* d_out, int out_size, void* d_ws, size_t ws_size,
                              hipStream_t stream) {
  const float* x = (const float*)d_in[0];
  const float* adj = (const float*)d_in[1];
  const float* lambdas = (const float*)d_in[2];
  const float* thetas = (const float*)d_in[3];
  char* ws = (char*)d_ws;
  float* S = (float*)ws;                                   // 64 KiB
  unsigned short* thT = (unsigned short*)(ws + 65536);     // 64 KiB (both layers)
  unsigned short* adjk = (unsigned short*)(ws + 131072);   // 2 x 16 MiB
  unsigned short* hT2 = (unsigned short*)(ws + 131072 + 33554432);  // 64 MiB
  unsigned short* hTd = (unsigned short*)d_out;            // 64 MiB scratch inside d_out
                                                           // (dead before final out-write)
  akgcn_prep<<<16386, 256, 0, stream>>>(adj, lambdas, thetas, S, thT, adjk);
  akgcn_gemm1<<<2048, 256, 0, stream>>>(x, thT, hTd);
  akgcn_gemm2<0><<<2048, 256, 0, stream>>>(adjk, hTd, S, lambdas, nullptr, thT + 16384, hT2);
  akgcn_gemm2<1><<<2048, 256, 0, stream>>>(adjk + 8388608ull, hT2, S, lambdas, x, nullptr, d_out);
}